// Round 2
// baseline (464.925 us; speedup 1.0000x reference)
//
#include <hip/hip_runtime.h>

#define NJ  55
#define BLK 256
#define VPT 2   // vertices per thread, 256 apart -> same alignment phase p

// Design: weights rows (stride 220 B) are read directly from global with
// aligned float4: row n is 16B-aligned starting at joint p=n&3 (since
// (55n+p)*4 % 16 == 0). 13 float4 cover j=p..p+51; 3 scalar tail joints
// (p+52+i) mod 55 cover the rest. SE3 (55x12 floats) lives in LDS (2.6 KB),
// so occupancy is VGPR-limited (~6 waves/SIMD), not LDS-limited.
__global__ __launch_bounds__(BLK, 6) void lbs_kernel(
    const float* __restrict__ points,
    const float* __restrict__ weights,
    const float* __restrict__ se3,
    float* __restrict__ out,
    int n_verts)
{
    __shared__ __align__(16) float sm[NJ * 12];

    const int tid = threadIdx.x;
    // one-time stage of SE3 rows 0..2 (12 floats/joint, contiguous per joint)
    for (int i = tid; i < NJ * 12; i += BLK) {
        const int j = i / 12;
        sm[i] = se3[j * 16 + (i - j * 12)];
    }
    __syncthreads();

    const int base = blockIdx.x * (BLK * VPT) + tid;
    const int p = base & 3;   // = tid&3 (block base is a multiple of 4)

    int nact[VPT];
    int nc[VPT];
    const float4* wrow[VPT];
    #pragma unroll
    for (int v = 0; v < VPT; ++v) {
        const int n = base + v * BLK;
        nact[v] = n;
        // alignment-preserving clamp for inactive lanes (keeps same p, in-bounds)
        nc[v] = (n < n_verts) ? n : (n_verts - 4 + p);
        wrow[v] = (const float4*)(weights + (size_t)nc[v] * NJ + p);
    }

    float a[VPT][12];
    #pragma unroll
    for (int v = 0; v < VPT; ++v)
        #pragma unroll
        for (int e = 0; e < 12; ++e) a[v][e] = 0.f;

    #pragma unroll 2
    for (int k = 0; k < 13; ++k) {
        float w[VPT][4];
        #pragma unroll
        for (int v = 0; v < VPT; ++v) {
            const float4 t = wrow[v][k];
            w[v][0] = t.x; w[v][1] = t.y; w[v][2] = t.z; w[v][3] = t.w;
        }
        #pragma unroll
        for (int c = 0; c < 4; ++c) {
            // 4 distinct joints across the wave (p in 0..3), 16-lane broadcast each:
            // bank quads disjoint -> conflict-free
            const float4* sj = (const float4*)&sm[(p + 4 * k + c) * 12];
            const float4 s0 = sj[0];
            const float4 s1 = sj[1];
            const float4 s2 = sj[2];
            #pragma unroll
            for (int v = 0; v < VPT; ++v) {
                const float wc = w[v][c];
                a[v][0] += wc * s0.x; a[v][1] += wc * s0.y; a[v][2]  += wc * s0.z; a[v][3]  += wc * s0.w;
                a[v][4] += wc * s1.x; a[v][5] += wc * s1.y; a[v][6]  += wc * s1.z; a[v][7]  += wc * s1.w;
                a[v][8] += wc * s2.x; a[v][9] += wc * s2.y; a[v][10] += wc * s2.z; a[v][11] += wc * s2.w;
            }
        }
    }

    // 3 tail joints: j = (p+52+i) mod 55 — exactly the joints not covered above
    #pragma unroll
    for (int i = 0; i < 3; ++i) {
        int j = p + 52 + i;
        if (j >= NJ) j -= NJ;
        const float4* sj = (const float4*)&sm[j * 12];
        const float4 s0 = sj[0];
        const float4 s1 = sj[1];
        const float4 s2 = sj[2];
        #pragma unroll
        for (int v = 0; v < VPT; ++v) {
            const float wc = weights[(size_t)nc[v] * NJ + j];
            a[v][0] += wc * s0.x; a[v][1] += wc * s0.y; a[v][2]  += wc * s0.z; a[v][3]  += wc * s0.w;
            a[v][4] += wc * s1.x; a[v][5] += wc * s1.y; a[v][6]  += wc * s1.z; a[v][7]  += wc * s1.w;
            a[v][8] += wc * s2.x; a[v][9] += wc * s2.y; a[v][10] += wc * s2.z; a[v][11] += wc * s2.w;
        }
    }

    #pragma unroll
    for (int v = 0; v < VPT; ++v) {
        const float* pp = points + (size_t)nc[v] * 3;
        const float px = pp[0];
        const float py = pp[1];
        const float pz = pp[2];
        if (nact[v] < n_verts) {
            float* po = out + (size_t)nact[v] * 3;
            po[0] = a[v][0] * px + a[v][1] * py + a[v][2]  * pz + a[v][3];
            po[1] = a[v][4] * px + a[v][5] * py + a[v][6]  * pz + a[v][7];
            po[2] = a[v][8] * px + a[v][9] * py + a[v][10] * pz + a[v][11];
        }
    }
}

extern "C" void kernel_launch(void* const* d_in, const int* in_sizes, int n_in,
                              void* d_out, int out_size, void* d_ws, size_t ws_size,
                              hipStream_t stream) {
    const float* points  = (const float*)d_in[0];
    const float* weights = (const float*)d_in[1];
    const float* se3     = (const float*)d_in[2];
    float* out = (float*)d_out;

    const int n_verts = in_sizes[0] / 3;  // points is (N,3)
    const int per_block = BLK * VPT;
    const int grid = (n_verts + per_block - 1) / per_block;
    lbs_kernel<<<grid, BLK, 0, stream>>>(points, weights, se3, out, n_verts);
}

// Round 3
// 317.221 us; speedup vs baseline: 1.4656x; 1.4656x over previous
//
#include <hip/hip_runtime.h>

#define NJ  55
#define BLK 64                 // one wave per block: no __syncthreads needed
#define SLAB (BLK * NJ)        // 3520 floats = 14080 B LDS -> 11 blocks/CU

// Wave-autonomous LBS:
//  - each 64-lane block stages its contiguous 64x55 weight slab into its own
//    LDS region with coalesced float4 loads (ideal HBM fetch, each line read once)
//  - no block barrier: wave stages, waits, computes -> 11 independent waves/CU
//    overlap staging and compute across waves
//  - weights row read from LDS at stride 55 (odd -> <=2-way bank aliasing, free)
//  - SE3 read at wave-uniform addresses from global (const restrict) -> scalar
//    s_load + K$ hits, keeping the DS pipe for weights only
__global__ __launch_bounds__(BLK) void lbs_kernel(
    const float* __restrict__ points,
    const float* __restrict__ weights,
    const float* __restrict__ se3,
    float* __restrict__ out,
    int n_verts)
{
    __shared__ __align__(16) float s_w[SLAB];

    const int lane = threadIdx.x;
    const int row0 = blockIdx.x * BLK;

    // ---- stage: coalesced float4 slab load (slab base offset 14080B % 16 == 0)
    if (row0 + BLK <= n_verts) {
        const float4* src = (const float4*)(weights + (size_t)row0 * NJ);
        float4* dst = (float4*)s_w;
        #pragma unroll
        for (int i = 0; i < SLAB / 4 / BLK; ++i)           // 13 full rounds
            dst[lane + i * BLK] = src[lane + i * BLK];
        const int tail = SLAB / 4 - (SLAB / 4 / BLK) * BLK; // 48 remaining float4
        if (lane < tail)
            dst[lane + (SLAB / 4 / BLK) * BLK] = src[lane + (SLAB / 4 / BLK) * BLK];
    } else {
        const int total = (n_verts - row0) * NJ;
        const float* src = weights + (size_t)row0 * NJ;
        for (int i = lane; i < total; i += BLK) s_w[i] = src[i];
    }
    __builtin_amdgcn_s_waitcnt(0);   // drain lgkm (ds_write) + vm; wave-private, no barrier
    // (compiler also inserts waits before dependent ds_read; this is belt&braces)

    const int n = row0 + lane;
    if (n >= n_verts) return;

    float a[12];
    #pragma unroll
    for (int e = 0; e < 12; ++e) a[e] = 0.f;

    const float* wr = &s_w[lane * NJ];          // stride 55: conflict-free
    const float4* M = (const float4*)se3;       // uniform addr -> s_load, K$

    #pragma unroll 5
    for (int j = 0; j < NJ; ++j) {
        const float w = wr[j];
        const float4 r0 = M[j * 4 + 0];
        const float4 r1 = M[j * 4 + 1];
        const float4 r2 = M[j * 4 + 2];         // row 3 of each SE3 unused
        a[0] += w * r0.x; a[1] += w * r0.y; a[2]  += w * r0.z; a[3]  += w * r0.w;
        a[4] += w * r1.x; a[5] += w * r1.y; a[6]  += w * r1.z; a[7]  += w * r1.w;
        a[8] += w * r2.x; a[9] += w * r2.y; a[10] += w * r2.z; a[11] += w * r2.w;
    }

    const float px = points[n * 3 + 0];
    const float py = points[n * 3 + 1];
    const float pz = points[n * 3 + 2];

    out[n * 3 + 0] = a[0] * px + a[1] * py + a[2]  * pz + a[3];
    out[n * 3 + 1] = a[4] * px + a[5] * py + a[6]  * pz + a[7];
    out[n * 3 + 2] = a[8] * px + a[9] * py + a[10] * pz + a[11];
}

extern "C" void kernel_launch(void* const* d_in, const int* in_sizes, int n_in,
                              void* d_out, int out_size, void* d_ws, size_t ws_size,
                              hipStream_t stream) {
    const float* points  = (const float*)d_in[0];
    const float* weights = (const float*)d_in[1];
    const float* se3     = (const float*)d_in[2];
    float* out = (float*)d_out;

    const int n_verts = in_sizes[0] / 3;          // points is (N,3)
    const int grid = (n_verts + BLK - 1) / BLK;   // 1e6/64 = 15625 exactly
    lbs_kernel<<<grid, BLK, 0, stream>>>(points, weights, se3, out, n_verts);
}